// Round 10
// baseline (198.704 us; speedup 1.0000x reference)
//
#include <hip/hip_runtime.h>
#include <hip/hip_bf16.h>
#include <hip/hip_fp8.h>

#define N_NODES 20000
#define DIM 128
#define N_EDGES 500000
#define BATCH 16384
#define EPS 1e-6f
#define L2E 1.4426950408889634f

typedef float f32x4 __attribute__((ext_vector_type(4)));
typedef float f32x2 __attribute__((ext_vector_type(2)));
typedef long long i64_t;

__device__ __forceinline__ float fast_sqrtf(float x) {
#if __has_builtin(__builtin_amdgcn_sqrtf)
    return __builtin_amdgcn_sqrtf(x);
#else
    return sqrtf(x);
#endif
}
__device__ __forceinline__ float fast_exp2f(float x) {
#if __has_builtin(__builtin_amdgcn_exp2f)
    return __builtin_amdgcn_exp2f(x);
#else
    return exp2f(x);
#endif
}
__device__ __forceinline__ f32x2 splat2(float s) { f32x2 r = {s, s}; return r; }
__device__ __forceinline__ f32x2 max2(f32x2 a, f32x2 b) {
#if __has_builtin(__builtin_elementwise_max)
    return __builtin_elementwise_max(a, b);
#else
    f32x2 r; r.x = fmaxf(a.x, b.x); r.y = fmaxf(a.y, b.y); return r;
#endif
}

// pack 4 fp32 -> 4 fp8 e4m3 (OCP on gfx950)
__device__ __forceinline__ unsigned pack4_fp8(float a, float b, float c, float d) {
#if __has_builtin(__builtin_amdgcn_cvt_pk_fp8_f32)
    unsigned v = 0;
    v = __builtin_amdgcn_cvt_pk_fp8_f32(a, b, v, false);
    v = __builtin_amdgcn_cvt_pk_fp8_f32(c, d, v, true);
    return v;
#else
    __hip_fp8_e4m3 x0(a), x1(b), x2(c), x3(d);
    return (unsigned)x0.__x | ((unsigned)x1.__x << 8) |
           ((unsigned)x2.__x << 16) | ((unsigned)x3.__x << 24);
#endif
}

template <bool HI>
__device__ __forceinline__ f32x2 unpack2_fp8(unsigned v) {
#if __has_builtin(__builtin_amdgcn_cvt_pk_f32_fp8)
    return __builtin_amdgcn_cvt_pk_f32_fp8((int)v, HI);
#else
    __hip_fp8_e4m3 t0, t1;
    t0.__x = (unsigned char)(HI ? (v >> 16) : v);
    t1.__x = (unsigned char)(HI ? (v >> 24) : (v >> 8));
    f32x2 r; r.x = (float)t0; r.y = (float)t1;
    return r;
#endif
}

// ---- workspace layout (bytes) ----
#define OFF_N2A   0                // gathered |ps|^2 for A rows (16384*4)
#define OFF_N2B   65536
#define OFF_BA    131072           // gathered L2E*beta_ps
#define OFF_BB    196608           // gathered L2E*beta_p
#define OFF_A8    262144           // gathered p_star rows fp8 (16384*128)
#define OFF_B8    2359296          // gathered p rows fp8
#define OFF_P8    4456448          // full fp8 p (20000*128)
#define OFF_PS8   7016448          // full fp8 p_star
#define OFF_N2PT  9576448          // full-table |p_i|^2 (20000*4)
#define OFF_N2PST 9656448          // full-table |ps_i|^2
#define OFF_BTP   9736448          // L2E*beta_p table
#define OFF_BTPS  9816448          // L2E*beta_p_star table
#define OFF_END   9896448          // ~9.4 MB

// prep1: streaming convert fp32->fp8 of both tables + per-row norms + scaled betas.
__global__ __launch_bounds__(256) void prep1_kernel(
    const float* __restrict__ p, const float* __restrict__ ps,
    const float* __restrict__ beta_p, const float* __restrict__ beta_ps,
    unsigned char* __restrict__ p8, unsigned char* __restrict__ ps8,
    float* __restrict__ n2pt, float* __restrict__ n2pst,
    float* __restrict__ btp, float* __restrict__ btps,
    float* __restrict__ out)
{
    const int b = blockIdx.x;
    if (b == 0 && threadIdx.x == 0) out[0] = 0.f;
    if (b < 5000) {
        const bool isP = b < 2500;
        const float* src = isP ? p : ps;
        unsigned char* dst = isP ? p8 : ps8;
        float* n2t = isP ? n2pt : n2pst;
        const int g = threadIdx.x & 31;
        const int row = (isP ? b : b - 2500) * 8 + (threadIdx.x >> 5);
        float4 v = ((const float4*)(src + (size_t)row * DIM))[g];
        ((unsigned*)(dst + (size_t)row * DIM))[g] = pack4_fp8(v.x, v.y, v.z, v.w);
        float nrm = v.x * v.x + v.y * v.y + v.z * v.z + v.w * v.w;
        #pragma unroll
        for (int m = 16; m >= 1; m >>= 1) nrm += __shfl_xor(nrm, m, 32);
        if (g == 0) n2t[row] = nrm;
    } else {
        int t = (b - 5000) * 256 + threadIdx.x;
        if (t < N_NODES) btp[t] = L2E * beta_p[t];
        else if (t < 2 * N_NODES) btps[t - N_NODES] = L2E * beta_ps[t - N_NODES];
    }
}

// prep2: gather fp8 rows + norms + scaled betas for the batch index sets.
// 1024 blocks x 256 thr; 32 rows/block, 8 lanes/row.
__global__ __launch_bounds__(256) void prep2_kernel(
    const int* __restrict__ nodes_ps, const int* __restrict__ nodes_p,
    const unsigned char* __restrict__ p8, const unsigned char* __restrict__ ps8,
    const float* __restrict__ n2pt, const float* __restrict__ n2pst,
    const float* __restrict__ btp, const float* __restrict__ btps,
    unsigned char* __restrict__ A8, float* __restrict__ n2A, float* __restrict__ bA2,
    unsigned char* __restrict__ B8, float* __restrict__ n2B, float* __restrict__ bB2)
{
    const int b = blockIdx.x;
    const bool isA = b < 512;
    const int row = (isA ? b : b - 512) * 32 + (threadIdx.x >> 3);
    const int l8 = threadIdx.x & 7;
    const int id = isA ? nodes_ps[row] : nodes_p[row];
    const unsigned char* tbl = isA ? ps8 : p8;
    unsigned char* dst = isA ? A8 : B8;
    uint4 v = *(const uint4*)(tbl + (size_t)id * DIM + l8 * 16);
    *(uint4*)(dst + (size_t)row * DIM + l8 * 16) = v;
    if (l8 == 0) {
        if (isA) { n2A[row] = n2pst[id]; bA2[row] = btps[id]; }
        else     { n2B[row] = n2pt[id];  bB2[row] = btp[id]; }
    }
}

// Main: 8256 blocks x 512 threads. One 128x128 fp8 tile (8 waves, 32x64 each)
// + 64 fused link edges per block. Single staging barrier drains ONLY the tile
// staging + edge-index loads; all dependent gathers and epilogue operand loads
// issue post-barrier and hide under MFMA+epilogue.
#define LSTRIDE 144   // 128 data + 16 pad bytes
__global__ __launch_bounds__(512, 4) void main_kernel(
    const unsigned char* __restrict__ Ag, const unsigned char* __restrict__ Bg,
    const float* __restrict__ n2A, const float* __restrict__ n2B,
    const float* __restrict__ bA2, const float* __restrict__ bB2,
    const int* __restrict__ edges,
    const float* __restrict__ beta_p, const float* __restrict__ beta_ps,
    const unsigned char* __restrict__ p8, const unsigned char* __restrict__ ps8,
    float* __restrict__ out)
{
    const int bx = blockIdx.x, by = blockIdx.y;   // grid (129, 64)
    int ti, tj;
    const int len = 128 - by;
    if (bx < len) { ti = by; tj = by + bx; }
    else          { ti = 127 - by; tj = 127 - (bx - len); }
    const int i0 = ti * 128, j0 = tj * 128;
    const int bid = by * 129 + bx;
    const bool diag = (ti == tj);

    __shared__ __align__(16) unsigned char As[128 * LSTRIDE];
    __shared__ __align__(16) unsigned char Bs[128 * LSTRIDE];
    __shared__ float smr[8];

    const int tid = threadIdx.x;
    const int lane = tid & 63;
    const int w = tid >> 6;
    const int wm = w & 3;         // 32-row quarter
    const int wn = w >> 2;        // 64-col half
    const int quad = lane >> 4;
    const int lr = lane & 15;

    // ---- pre-barrier: edge indices + betas (tiny, independent) ----
    const int le = bid * 64 + w * 8 + (lane >> 3);
    const int lch = lane & 7;
    const bool ev = (le < N_EDGES);
    int e0 = 0, e1 = 0;
    float ebeta = 0.f;
    if (ev) {
        e0 = edges[le];
        e1 = edges[N_EDGES + le];
        if (lch == 0) ebeta = beta_ps[e0] + beta_p[e1];
    }

    // ---- stage both fp8 tiles: 1024 16B chunks per array, 2/thread/array ----
    #pragma unroll
    for (int c = tid; c < 1024; c += 512) {
        int row = c >> 3, col = (c & 7) * 16;
        *(uint4*)&As[row * LSTRIDE + col] = *(const uint4*)(Ag + (size_t)(i0 + row) * DIM + col);
        *(uint4*)&Bs[row * LSTRIDE + col] = *(const uint4*)(Bg + (size_t)(j0 + row) * DIM + col);
    }
    __syncthreads();

    // ---- post-barrier: link row gathers + epilogue operands (hidden under MFMA) ----
    uint4 ua = {0,0,0,0}, ub = {0,0,0,0};
    if (ev) {
        ua = *(const uint4*)(p8 + (size_t)e0 * DIM + lch * 16);
        ub = *(const uint4*)(ps8 + (size_t)e1 * DIM + lch * 16);
    }
    const int ilo = i0 + wm * 32, jlo = j0 + wn * 64;
    float4 n2i[2], bi[2];
    #pragma unroll
    for (int mi = 0; mi < 2; ++mi) {
        n2i[mi] = *(const float4*)&n2A[ilo + mi * 16 + quad * 4];
        bi[mi]  = *(const float4*)&bA2[ilo + mi * 16 + quad * 4];
    }
    float n2j[4], bj[4];
    #pragma unroll
    for (int ni = 0; ni < 4; ++ni) {
        n2j[ni] = n2B[jlo + ni * 16 + lr];
        bj[ni]  = bB2[jlo + ni * 16 + lr];
    }

    // wave class on diagonal tiles: 0=free (all j>i), 1=masked, 2=dead
    int cls = 0;
    if (diag) cls = (wn == 0) ? (wm >= 2 ? 2 : 1) : (wm >= 2 ? 1 : 0);

    float lsum = 0.f;
    f32x2 lsum2 = {0.f, 0.f};
    if (cls != 2) {
        f32x4 acc[2][4] = {};
        #pragma unroll
        for (int ks = 0; ks < 4; ++ks) {
            int koff = ks * 32 + quad * 8;
            i64_t af[2], bf[4];
            #pragma unroll
            for (int u = 0; u < 2; ++u)
                af[u] = *(const i64_t*)&As[(wm * 32 + u * 16 + lr) * LSTRIDE + koff];
            #pragma unroll
            for (int v = 0; v < 4; ++v)
                bf[v] = *(const i64_t*)&Bs[(wn * 64 + v * 16 + lr) * LSTRIDE + koff];
            #pragma unroll
            for (int mi = 0; mi < 2; ++mi)
                #pragma unroll
                for (int ni = 0; ni < 4; ++ni)
                    acc[mi][ni] = __builtin_amdgcn_mfma_f32_16x16x32_fp8_fp8(af[mi], bf[ni], acc[mi][ni], 0, 0, 0);
        }

        // epilogue: C/D layout col=lane&15, row=quad*4+reg
        if (cls == 0) {
            #pragma unroll
            for (int mi = 0; mi < 2; ++mi) {
                f32x2 n2iA = {n2i[mi].x, n2i[mi].y}, n2iB = {n2i[mi].z, n2i[mi].w};
                f32x2 biA  = {bi[mi].x,  bi[mi].y},  biB  = {bi[mi].z,  bi[mi].w};
                #pragma unroll
                for (int ni = 0; ni < 4; ++ni) {
                    f32x4 d = acc[mi][ni];
                    f32x2 d0 = {d[0], d[1]}, d1 = {d[2], d[3]};
                    f32x2 bsum0 = biA + splat2(bj[ni]);
                    f32x2 bsum1 = biB + splat2(bj[ni]);
                    f32x2 sq0 = max2(d0 * splat2(-2.f) + (n2iA + splat2(n2j[ni])), splat2(0.f));
                    f32x2 sq1 = max2(d1 * splat2(-2.f) + (n2iB + splat2(n2j[ni])), splat2(0.f));
                    f32x2 dist0 = {fast_sqrtf(sq0.x), fast_sqrtf(sq0.y)};
                    f32x2 dist1 = {fast_sqrtf(sq1.x), fast_sqrtf(sq1.y)};
                    f32x2 arg0 = dist0 * splat2(-L2E) + bsum0;
                    f32x2 arg1 = dist1 * splat2(-L2E) + bsum1;
                    f32x2 ex0 = {fast_exp2f(arg0.x), fast_exp2f(arg0.y)};
                    f32x2 ex1 = {fast_exp2f(arg1.x), fast_exp2f(arg1.y)};
                    lsum2 += ex0 + ex1;
                }
            }
        } else {
            #pragma unroll
            for (int mi = 0; mi < 2; ++mi)
                #pragma unroll
                for (int ni = 0; ni < 4; ++ni) {
                    f32x4 d = acc[mi][ni];
                    #pragma unroll
                    for (int r = 0; r < 4; ++r) {
                        int ig = ilo + mi * 16 + quad * 4 + r;
                        int jg = jlo + ni * 16 + lr;
                        float tt = ((const float*)&n2i[mi])[r] + n2j[ni];
                        float sq = fmaxf(fmaf(d[r], -2.f, tt), 0.f);
                        float arg = fmaf(fast_sqrtf(sq), -L2E, ((const float*)&bi[mi])[r] + bj[ni]);
                        float ex = fast_exp2f(arg);
                        if (jg > ig) lsum += ex;
                    }
                }
        }
    }
    lsum += lsum2.x + lsum2.y;

    // ---- link math: fp8 rows arrived long ago ----
    if (ev) {
        float s = 0.f;
        #pragma unroll
        for (int d = 0; d < 4; ++d) {
            unsigned va = ((const unsigned*)&ua)[d];
            unsigned vb = ((const unsigned*)&ub)[d];
            f32x2 a0 = unpack2_fp8<false>(va), a1 = unpack2_fp8<true>(va);
            f32x2 b0 = unpack2_fp8<false>(vb), b1 = unpack2_fp8<true>(vb);
            float t0 = a0.x - b0.x + EPS, t1 = a0.y - b0.y + EPS;
            float t2 = a1.x - b1.x + EPS, t3 = a1.y - b1.y + EPS;
            s = fmaf(t0, t0, s); s = fmaf(t1, t1, s);
            s = fmaf(t2, t2, s); s = fmaf(t3, t3, s);
        }
        #pragma unroll
        for (int m = 4; m >= 1; m >>= 1) s += __shfl_xor(s, m, 8);
        if (lch == 0) lsum -= ebeta - fast_sqrtf(s);
    }

    #pragma unroll
    for (int m = 32; m >= 1; m >>= 1) lsum += __shfl_xor(lsum, m, 64);
    if (lane == 0) smr[w] = lsum;
    __syncthreads();
    if (tid == 0) {
        float t = 0.f;
        #pragma unroll
        for (int i = 0; i < 8; ++i) t += smr[i];
        atomicAdd(out, t);
    }
}

extern "C" void kernel_launch(void* const* d_in, const int* in_sizes, int n_in,
                              void* d_out, int out_size, void* d_ws, size_t ws_size,
                              hipStream_t stream) {
    const int* edges = (const int*)d_in[0];
    const int* nodes_p_star = (const int*)d_in[1];
    const int* nodes_p = (const int*)d_in[2];
    const float* beta_p = (const float*)d_in[3];
    const float* beta_p_star = (const float*)d_in[4];
    const float* p = (const float*)d_in[5];
    const float* p_star = (const float*)d_in[6];

    char* ws = (char*)d_ws;
    float* n2A = (float*)(ws + OFF_N2A);
    float* n2B = (float*)(ws + OFF_N2B);
    float* bA2 = (float*)(ws + OFF_BA);
    float* bB2 = (float*)(ws + OFF_BB);
    unsigned char* A8 = (unsigned char*)(ws + OFF_A8);
    unsigned char* B8 = (unsigned char*)(ws + OFF_B8);
    unsigned char* p8 = (unsigned char*)(ws + OFF_P8);
    unsigned char* ps8 = (unsigned char*)(ws + OFF_PS8);
    float* n2pt = (float*)(ws + OFF_N2PT);
    float* n2pst = (float*)(ws + OFF_N2PST);
    float* btp = (float*)(ws + OFF_BTP);
    float* btps = (float*)(ws + OFF_BTPS);

    prep1_kernel<<<5157, 256, 0, stream>>>(
        p, p_star, beta_p, beta_p_star, p8, ps8, n2pt, n2pst, btp, btps, (float*)d_out);

    prep2_kernel<<<1024, 256, 0, stream>>>(
        nodes_p_star, nodes_p, p8, ps8, n2pt, n2pst, btp, btps,
        A8, n2A, bA2, B8, n2B, bB2);

    main_kernel<<<dim3(129, 64), 512, 0, stream>>>(
        A8, B8, n2A, n2B, bA2, bB2,
        edges, beta_p, beta_p_star, p8, ps8, (float*)d_out);
}